// Round 2
// baseline (369.405 us; speedup 1.0000x reference)
//
#include <hip/hip_runtime.h>
#include <hip/hip_bf16.h>

#define IN_F 8192
#define OUT_F 8192
#define STATE_THRESHOLD 50.0f

// One wave (64 lanes) handles TWO output rows (two independent HBM streams,
// two accumulators -> 2x loads in flight). Block = 256 threads = 4 waves =
// 8 rows. Grid = 1024 blocks -> 4 blocks/CU, all co-resident (LDS cap is 5
// at 32 KiB/block), single dispatch round, no tail.
__global__ __launch_bounds__(256) void snn_gemv_kernel(
    const float* __restrict__ spike_input,      // [IN_F]
    const float* __restrict__ synapse_states,   // [OUT_F, IN_F]
    const float* __restrict__ membrane,         // [OUT_F]
    const float* __restrict__ adaptive_thresh,  // [OUT_F]
    const float* __restrict__ noise,            // [OUT_F]
    float* __restrict__ out)                    // [OUT_F]
{
    __shared__ float s_spike[IN_F];             // 32 KiB

    const int tid  = threadIdx.x;               // 0..255
    const int lane = tid & 63;
    const int wave = tid >> 6;                  // 0..3

    // Stage spike vector: 2048 float4, 256 threads -> 8 each, coalesced.
    const float4* sp4 = (const float4*)spike_input;
    float4* ls4 = (float4*)s_spike;
#pragma unroll
    for (int j = 0; j < 8; ++j) {
        ls4[tid + 256 * j] = sp4[tid + 256 * j];
    }
    __syncthreads();

    const int row0 = blockIdx.x * 8 + wave * 2; // two consecutive rows
    const float4* r0 = (const float4*)(synapse_states + (size_t)row0 * IN_F);
    const float4* r1 = (const float4*)(synapse_states + (size_t)(row0 + 1) * IN_F);
    const float4* lsp = (const float4*)s_spike;

    float acc0 = 0.0f, acc1 = 0.0f;
    // 2048 float4 per row / 64 lanes = 32 iters; unroll 4 -> 8 global float4
    // loads (8 KiB/wave) in flight per batch.
#pragma unroll 4
    for (int k = lane; k < IN_F / 4; k += 64) {
        float4 s0 = r0[k];
        float4 s1 = r1[k];
        float4 x  = lsp[k];
        acc0 += (s0.x > STATE_THRESHOLD ? x.x : 0.0f);
        acc0 += (s0.y > STATE_THRESHOLD ? x.y : 0.0f);
        acc0 += (s0.z > STATE_THRESHOLD ? x.z : 0.0f);
        acc0 += (s0.w > STATE_THRESHOLD ? x.w : 0.0f);
        acc1 += (s1.x > STATE_THRESHOLD ? x.x : 0.0f);
        acc1 += (s1.y > STATE_THRESHOLD ? x.y : 0.0f);
        acc1 += (s1.z > STATE_THRESHOLD ? x.z : 0.0f);
        acc1 += (s1.w > STATE_THRESHOLD ? x.w : 0.0f);
    }

    // Wave-level reductions across 64 lanes.
#pragma unroll
    for (int off = 32; off > 0; off >>= 1) {
        acc0 += __shfl_down(acc0, off);
        acc1 += __shfl_down(acc1, off);
    }

    if (lane == 0) {
        float p0 = membrane[row0] + acc0 + noise[row0];
        float p1 = membrane[row0 + 1] + acc1 + noise[row0 + 1];
        out[row0]     = (p0 >= adaptive_thresh[row0]) ? 1.0f : 0.0f;
        out[row0 + 1] = (p1 >= adaptive_thresh[row0 + 1]) ? 1.0f : 0.0f;
    }
}

extern "C" void kernel_launch(void* const* d_in, const int* in_sizes, int n_in,
                              void* d_out, int out_size, void* d_ws, size_t ws_size,
                              hipStream_t stream) {
    const float* spike_input    = (const float*)d_in[0];
    const float* synapse_states = (const float*)d_in[1];
    const float* membrane       = (const float*)d_in[2];
    const float* adaptive_thr   = (const float*)d_in[3];
    const float* noise          = (const float*)d_in[4];
    float* out = (float*)d_out;

    dim3 grid(OUT_F / 8);   // 1024 blocks, 8 rows per block (2 per wave)
    dim3 block(256);
    snn_gemv_kernel<<<grid, block, 0, stream>>>(
        spike_input, synapse_states, membrane, adaptive_thr, noise, out);
}

// Round 3
// 364.205 us; speedup vs baseline: 1.0143x; 1.0143x over previous
//
#include <hip/hip_runtime.h>
#include <hip/hip_bf16.h>

#define IN_F 8192
#define OUT_F 8192
#define STATE_THRESHOLD 50.0f

// One wave per output row. Block = 512 threads = 8 waves = 8 rows, sharing
// one 32 KiB LDS copy of the spike vector. 4 blocks/CU (wave-capped) =
// 32 waves/CU = 100% occupancy; grid of 1024 blocks is fully co-resident.
// __launch_bounds__(512,8) caps VGPRs at 64 so 8 waves/SIMD actually fit.
__global__ __launch_bounds__(512, 8) void snn_gemv_kernel(
    const float* __restrict__ spike_input,      // [IN_F]
    const float* __restrict__ synapse_states,   // [OUT_F, IN_F]
    const float* __restrict__ membrane,         // [OUT_F]
    const float* __restrict__ adaptive_thresh,  // [OUT_F]
    const float* __restrict__ noise,            // [OUT_F]
    float* __restrict__ out)                    // [OUT_F]
{
    __shared__ float s_spike[IN_F];             // 32 KiB

    const int tid  = threadIdx.x;               // 0..511
    const int lane = tid & 63;
    const int wave = tid >> 6;                  // 0..7

    // Stage spike vector: 2048 float4, 512 threads -> 4 each, coalesced.
    const float4* sp4 = (const float4*)spike_input;
    float4* ls4 = (float4*)s_spike;
#pragma unroll
    for (int j = 0; j < 4; ++j) {
        ls4[tid + 512 * j] = sp4[tid + 512 * j];
    }
    __syncthreads();

    const int row = blockIdx.x * 8 + wave;
    const float4* rowp = (const float4*)(synapse_states + (size_t)row * IN_F);
    const float4* lsp  = (const float4*)s_spike;

    float acc = 0.0f;
    // 2048 float4 per row / 64 lanes = 32 iterations; unroll 4 -> 4 float4
    // global loads (4 KiB/wave) in flight per batch. 32 waves/CU keeps the
    // CU's memory queue fed while individual waves drain vmcnt.
#pragma unroll 4
    for (int k = lane; k < IN_F / 4; k += 64) {
        float4 s = rowp[k];
        float4 x = lsp[k];
        acc += (s.x > STATE_THRESHOLD ? x.x : 0.0f);
        acc += (s.y > STATE_THRESHOLD ? x.y : 0.0f);
        acc += (s.z > STATE_THRESHOLD ? x.z : 0.0f);
        acc += (s.w > STATE_THRESHOLD ? x.w : 0.0f);
    }

    // Wave-level reduction across 64 lanes.
#pragma unroll
    for (int off = 32; off > 0; off >>= 1) {
        acc += __shfl_down(acc, off);
    }

    if (lane == 0) {
        float potential = membrane[row] + acc + noise[row];
        out[row] = (potential >= adaptive_thresh[row]) ? 1.0f : 0.0f;
    }
}

extern "C" void kernel_launch(void* const* d_in, const int* in_sizes, int n_in,
                              void* d_out, int out_size, void* d_ws, size_t ws_size,
                              hipStream_t stream) {
    const float* spike_input    = (const float*)d_in[0];
    const float* synapse_states = (const float*)d_in[1];
    const float* membrane       = (const float*)d_in[2];
    const float* adaptive_thr   = (const float*)d_in[3];
    const float* noise          = (const float*)d_in[4];
    float* out = (float*)d_out;

    dim3 grid(OUT_F / 8);   // 1024 blocks, 8 rows per block (1 per wave)
    dim3 block(512);
    snn_gemv_kernel<<<grid, block, 0, stream>>>(
        spike_input, synapse_states, membrane, adaptive_thr, noise, out);
}